// Round 20
// baseline (79.914 us; speedup 1.0000x reference)
//
#include <hip/hip_runtime.h>

// CCQC classifier, GEMM formulation. R20: fused NLL accumulation.
//   gemm_z no longer stores 32 chunk partials (1 MB); each block atomicAdds
//   sign-folded row contributions into q0/q1/nn (3 x B floats, zeroed by
//   make_prog). nll_rows computes log-softmax NLL from 96 KB and atomicAdds
//   the scalar. Removes 2 MB of part[] traffic + a dispatch's worth of drain.
//   Rest: R19 structure -- 3 k-bit build (j=(k<<7)|(wv<<6)|lane, 128-thread
//   blocks, fused 69-op variant-table program), xconv fused into qprep,
//   gemm_z 128x128 BK=64 8-wave + XOR swizzle.

namespace {

typedef float f32x2 __attribute__((ext_vector_type(2)));
typedef __fp16 fp16x2 __attribute__((ext_vector_type(2)));
typedef _Float16 f16x8 __attribute__((ext_vector_type(8)));
typedef float f32x4v __attribute__((ext_vector_type(4)));

// ---- packed dual-f32 ops (VOP3P), untied operands ----
__device__ __forceinline__ f32x2 pk_mul(f32x2 a, f32x2 b) {
  f32x2 d;
  asm("v_pk_mul_f32 %0, %1, %2" : "=v"(d) : "v"(a), "v"(b));
  return d;
}
__device__ __forceinline__ f32x2 pk_fma(f32x2 a, f32x2 b, f32x2 c) {
  f32x2 d;
  asm("v_pk_fma_f32 %0, %1, %2, %3" : "=v"(d) : "v"(a), "v"(b), "v"(c));
  return d;
}
__device__ __forceinline__ f32x2 pk_fma_swap1(f32x2 a, f32x2 b, f32x2 c) {
  f32x2 d;
  asm("v_pk_fma_f32 %0, %1, %2, %3 op_sel:[0,1,0] op_sel_hi:[1,0,1]"
      : "=v"(d) : "v"(a), "v"(b), "v"(c));
  return d;
}
__device__ __forceinline__ f32x2 cmulp(f32x2 cr2, f32x2 ci2, f32x2 v) {
  return pk_fma_swap1(ci2, v, pk_mul(cr2, v));
}
__device__ __forceinline__ f32x2 cmad(f32x2 acc, f32x2 cr2, f32x2 ci2, f32x2 v) {
  return pk_fma_swap1(ci2, v, pk_fma(cr2, v, acc));
}

__device__ __forceinline__ f32x2 shfl_xor2(f32x2 v, int lm) {
  f32x2 r;
  r.x = __shfl_xor(v.x, lm, 64);
  r.y = __shfl_xor(v.y, lm, 64);
  return r;
}
template <int CTRL>
__device__ __forceinline__ f32x2 dpp_xor2(f32x2 v) {
  f32x2 r;
  const int ix = __builtin_bit_cast(int, v.x);
  const int iy = __builtin_bit_cast(int, v.y);
  r.x = __builtin_bit_cast(float,
      __builtin_amdgcn_update_dpp(0, ix, CTRL, 0xF, 0xF, true));
  r.y = __builtin_bit_cast(float,
      __builtin_amdgcn_update_dpp(0, iy, CTRL, 0xF, 0xF, true));
  return r;
}
__device__ __forceinline__ f32x2 shfl_fast(f32x2 v, const int lm) {
  if (lm == 1) return dpp_xor2<0xB1>(v);
  if (lm == 2) return dpp_xor2<0x4E>(v);
  return shfl_xor2(v, lm);
}

struct c2 { float r, i; };
struct m2c { c2 a00, a01, a10, a11; };

__device__ __forceinline__ c2 cmul(c2 x, c2 y) { return {x.r*y.r - x.i*y.i, x.r*y.i + x.i*y.r}; }
__device__ __forceinline__ c2 cadd(c2 x, c2 y) { return {x.r + y.r, x.i + y.i}; }
__device__ __forceinline__ c2 conjc(c2 a) { return {a.r, -a.i}; }
__device__ __forceinline__ m2c mmul(m2c A, m2c B) {
  m2c C;
  C.a00 = cadd(cmul(A.a00, B.a00), cmul(A.a01, B.a10));
  C.a01 = cadd(cmul(A.a00, B.a01), cmul(A.a01, B.a11));
  C.a10 = cadd(cmul(A.a10, B.a00), cmul(A.a11, B.a10));
  C.a11 = cadd(cmul(A.a10, B.a01), cmul(A.a11, B.a11));
  return C;
}
__device__ __forceinline__ m2c madj(m2c U) {
  return { conjc(U.a00), conjc(U.a10), conjc(U.a01), conjc(U.a11) };
}
__device__ __forceinline__ m2c mrx(float t) {
  float c = cosf(0.5f * t), s = sinf(0.5f * t);
  return { {c, 0.f}, {0.f, -s}, {0.f, -s}, {c, 0.f} };
}
__device__ __forceinline__ m2c mrz(float t) {
  float c = cosf(0.5f * t), s = sinf(0.5f * t);
  return { {c, -s}, {0.f, 0.f}, {0.f, 0.f}, {c, s} };
}

// fusable(d,i): CU[i](d) absorbs U1[i](d+1). r(d)=1 (d even): i>=1; r=3: i>=3.
__device__ __forceinline__ bool fusable(int d, int i) {
  return (d & 1) ? (i >= 3) : (i >= 1);
}

// Block 0 (threads <128): 69-op program (variant-table form, 64 floats/op;
// matrix form for bt>=7, coef form otherwise). All blocks: zero qa[3B], out.
__global__ __launch_bounds__(1024) void make_prog(
    const float* __restrict__ w, const float* __restrict__ w1,
    const float* __restrict__ w2, float* __restrict__ prog,
    float* __restrict__ qa, int B, float* __restrict__ outp) {
  const int gid = blockIdx.x * 1024 + threadIdx.x;
  if (gid < 3 * B) qa[gid] = 0.f;
  if (gid == 0) outp[0] = 0.f;
  if (blockIdx.x != 0 || threadIdx.x >= 128) return;

  const int t = threadIdx.x;
  int kind = -1, od = 0, oi = 0, p = 0;
  for (int dd = 0; dd < 5; ++dd) {
    const int d = 4 - dd;
    if (d == 4) { if (p == t) kind = 0; ++p; }
    for (int ii = 0; ii < 10; ++ii) {
      const int i = 9 - ii;
      if (p == t) { kind = (d <= 3 && fusable(d, i)) ? 2 : 1; od = d; oi = i; }
      ++p;
    }
    for (int ii = 0; ii < 10; ++ii) {
      const int i = 9 - ii;
      if (d >= 1 && fusable(d - 1, i)) continue;
      if (p == t) { kind = 3; od = d; oi = i; }
      ++p;
    }
  }
  if (kind < 0) return;

  auto u1mat = [&](int d, int i) -> m2c {
    const float* pw = w + (d * 10 + i) * 5;
    m2c U = mmul(mrx(pw[2]), mmul(mrz(pw[1]), mrx(pw[0])));
    if (i == 0 && d > 0) {
      m2c U0 = mmul(mrz(w2[d - 1]), mrx(w1[d - 1]));
      U = mmul(U, U0);
    }
    return U;
  };
  auto cumat = [&](int d, int i) -> m2c {
    const float* pw = w + (d * 10 + i) * 5;
    return mmul(mrx(pw[4]), mrz(pw[3]));
  };

  m2c M0{}, M1{};
  int bt = 9;
  if (kind == 0) {
    M0 = madj(mmul(mrz(w2[4]), mrx(w1[4]))); M1 = M0; bt = 9;
  } else if (kind == 1) {
    M1 = madj(cumat(od, oi));
    M0 = m2c{ {1.f, 0.f}, {0.f, 0.f}, {0.f, 0.f}, {1.f, 0.f} };
    bt = 9 - oi;
  } else if (kind == 2) {
    m2c V1 = madj(u1mat(od + 1, oi));
    m2c VC = madj(cumat(od, oi));
    M0 = V1; M1 = mmul(VC, V1);
    bt = 9 - oi;
  } else {
    M0 = madj(u1mat(od, oi)); M1 = M0; bt = 9 - oi;
  }

  float* o = prog + t * 64;
  if (bt >= 7) {
    const m2c* Ms[2] = {&M0, &M1};
    #pragma unroll
    for (int c = 0; c < 2; ++c) {
      const c2 e[4] = {Ms[c]->a00, Ms[c]->a01, Ms[c]->a10, Ms[c]->a11};
      #pragma unroll
      for (int q = 0; q < 4; ++q) {
        o[c*16 + q*4 + 0] = e[q].r; o[c*16 + q*4 + 1] = e[q].r;
        o[c*16 + q*4 + 2] = -e[q].i; o[c*16 + q*4 + 3] = e[q].i;
      }
    }
  } else {
    #pragma unroll
    for (int v = 0; v < 4; ++v) {
      const bool hi = (v & 1) != 0;
      const m2c& M = (v >> 1) ? M1 : M0;
      const c2 cA = hi ? M.a11 : M.a00;
      const c2 cB = hi ? M.a10 : M.a01;
      o[v*8+0] = cA.r; o[v*8+1] = cA.r; o[v*8+2] = -cA.i; o[v*8+3] = cA.i;
      o[v*8+4] = cB.r; o[v*8+5] = cB.r; o[v*8+6] = -cB.i; o[v*8+7] = cB.i;
    }
  }
}

struct CoefP { f32x2 Ar, Ai, Br, Bi; };
__device__ __forceinline__ CoefP ldcoef(const float* __restrict__ g, int v) {
  const float4* p = reinterpret_cast<const float4*>(g + v * 8);
  const float4 a = p[0], b = p[1];
  return { f32x2{a.x, a.y}, f32x2{a.z, a.w}, f32x2{b.x, b.y}, f32x2{b.z, b.w} };
}
struct MatP { f32x2 u00r, u00i, u01r, u01i, u10r, u10i, u11r, u11i; };
__device__ __forceinline__ MatP ldmat16(const float* __restrict__ g, int c) {
  const float4* p = reinterpret_cast<const float4*>(g + c * 16);
  const float4 a = p[0], b = p[1], cc = p[2], d = p[3];
  MatP m;
  m.u00r = f32x2{a.x, a.y};  m.u00i = f32x2{a.z, a.w};
  m.u01r = f32x2{b.x, b.y};  m.u01i = f32x2{b.z, b.w};
  m.u10r = f32x2{cc.x, cc.y}; m.u10i = f32x2{cc.z, cc.w};
  m.u11r = f32x2{d.x, d.y};  m.u11i = f32x2{d.z, d.w};
  return m;
}
__device__ __forceinline__ f32x2 capply(const CoefP& c, f32x2 own, f32x2 par) {
  return cmad(cmulp(c.Ar, c.Ai, own), c.Br, c.Bi, par);
}
__device__ __forceinline__ void mat_pair(const MatP& m, f32x2& a, f32x2& b) {
  const f32x2 na = cmad(cmulp(m.u00r, m.u00i, a), m.u01r, m.u01i, b);
  const f32x2 nb = cmad(cmulp(m.u10r, m.u10i, a), m.u11r, m.u11i, b);
  a = na; b = nb;
}

// One program op. j = (k<<7)|(wv<<6)|lane, k in [0,8), wv in {0,1}.
__device__ __forceinline__ void apply_op(f32x2 (&s)[8], f32x2* lxb, const int wv,
                                         const int lane, const float* __restrict__ g,
                                         const int bt, const int bc) {
  if (bt >= 7) {
    const int tm = 1 << (bt - 7);
    if (bc >= 7) {
      const int cb = bc - 7;
      const MatP m0 = ldmat16(g, 0), m1 = ldmat16(g, 1);
      #pragma unroll
      for (int k0 = 0; k0 < 8; ++k0) {
        if (k0 & tm) continue;
        const int k1 = k0 | tm;
        const MatP& m = ((k0 >> cb) & 1) ? m1 : m0;
        mat_pair(m, s[k0], s[k1]);
      }
    } else {
      int c = 0;
      if (bc == 6)      c = wv;
      else if (bc >= 0) c = (lane >> bc) & 1;
      const MatP m = ldmat16(g, c);
      #pragma unroll
      for (int k0 = 0; k0 < 8; ++k0) {
        if (k0 & tm) continue;
        const int k1 = k0 | tm;
        mat_pair(m, s[k0], s[k1]);
      }
    }
  } else if (bt == 6) {
    const int hi = wv;
    #pragma unroll
    for (int k = 0; k < 8; ++k) lxb[(wv * 8 + k) * 64 + lane] = s[k];
    __syncthreads();
    const int pw = wv ^ 1;
    f32x2 pp[8];
    #pragma unroll
    for (int k = 0; k < 8; ++k) pp[k] = lxb[(pw * 8 + k) * 64 + lane];
    if (bc >= 7) {
      const int cb = bc - 7;
      const CoefP c0 = ldcoef(g, hi), c1 = ldcoef(g, hi + 2);
      #pragma unroll
      for (int k = 0; k < 8; ++k) {
        const CoefP& cf = ((k >> cb) & 1) ? c1 : c0;
        s[k] = capply(cf, s[k], pp[k]);
      }
    } else {
      int c = 0;
      if (bc >= 0) c = (lane >> bc) & 1;
      const CoefP cf = ldcoef(g, hi + 2 * c);
      #pragma unroll
      for (int k = 0; k < 8; ++k) s[k] = capply(cf, s[k], pp[k]);
    }
  } else {
    const int lm = 1 << bt;
    const int hi = (lane >> bt) & 1;
    if (bc >= 7) {
      const int cb = bc - 7;
      const CoefP c0 = ldcoef(g, hi), c1 = ldcoef(g, hi + 2);
      #pragma unroll
      for (int k = 0; k < 8; ++k) {
        const CoefP& cf = ((k >> cb) & 1) ? c1 : c0;
        const f32x2 p = shfl_fast(s[k], lm);
        s[k] = capply(cf, s[k], p);
      }
    } else {
      int c = 0;
      if (bc == 6)      c = wv;
      else if (bc >= 0) c = (lane >> bc) & 1;
      const CoefP cf = ldcoef(g, hi + 2 * c);
      #pragma unroll
      for (int k = 0; k < 8; ++k) {
        const f32x2 p = shfl_fast(s[k], lm);
        s[k] = capply(cf, s[k], p);
      }
    }
  }
}

// Fused prep, 128-thread blocks. Blocks <1024: build row n=blockIdx of U.
// Blocks >=1024: xconv one batch row (832 cols, packed cvt).
__global__ __launch_bounds__(128) void qprep(const float* __restrict__ prog,
                                             const float* __restrict__ x,
                                             _Float16* __restrict__ Wt,
                                             _Float16* __restrict__ Xh) {
  const int tid = threadIdx.x;
  if (blockIdx.x >= 1024) {
    const int b = blockIdx.x - 1024;
    const int j = tid * 8;
    if (j >= 832) return;
    union { fp16x2 h2[4]; f16x8 h8; } u;
    if (j < 784) {
      const float4* p = reinterpret_cast<const float4*>(x + (size_t)b * 784 + j);
      const float4 v0 = p[0], v1 = p[1];
      u.h2[0] = __builtin_amdgcn_cvt_pkrtz(v0.x, v0.y);
      u.h2[1] = __builtin_amdgcn_cvt_pkrtz(v0.z, v0.w);
      u.h2[2] = __builtin_amdgcn_cvt_pkrtz(v1.x, v1.y);
      u.h2[3] = __builtin_amdgcn_cvt_pkrtz(v1.z, v1.w);
    } else {
      #pragma unroll
      for (int q = 0; q < 4; ++q) u.h2[q] = __builtin_amdgcn_cvt_pkrtz(0.f, 0.f);
    }
    *reinterpret_cast<f16x8*>(Xh + (size_t)b * 1024 + j) = u.h8;
    return;
  }

  // ---- build_W: 1 state, 8 regs/lane, 2 waves ----
  __shared__ f32x2 lx[2][1024];

  const int lane = tid & 63;
  const int wv = tid >> 6;
  const int n = blockIdx.x;

  f32x2 s[8];
  #pragma unroll
  for (int k = 0; k < 8; ++k) {
    const int j = (k << 7) | (wv << 6) | lane;
    s[k].x = (j == n) ? 1.f : 0.f;
    s[k].y = 0.f;
  }

  int p = 0, ph = 0;
  #pragma unroll
  for (int dd = 0; dd < 5; ++dd) {
    const int d = 4 - dd;
    if (d == 4) {
      apply_op(s, &lx[ph & 1][0], wv, lane, prog + p * 64, 9, -1);
      ++p;
    }
    const int r = (d & 1) ? 3 : 1;
    #pragma unroll
    for (int ii = 0; ii < 10; ++ii) {
      const int i = 9 - ii;
      const int c = (i + r) % 10;
      const int bt = 9 - i, bc = 9 - c;
      apply_op(s, &lx[ph & 1][0], wv, lane, prog + p * 64, bt, bc);
      ++p; if (bt == 6) ++ph;
    }
    #pragma unroll
    for (int ii = 0; ii < 10; ++ii) {
      const int i = 9 - ii;
      if (d >= 1 && fusable(d - 1, i)) continue;
      const int bt = 9 - i;
      apply_op(s, &lx[ph & 1][0], wv, lane, prog + p * 64, bt, -1);
      ++p; if (bt == 6) ++ph;
    }
  }

  #pragma unroll
  for (int k = 0; k < 8; ++k) {
    const int j = (k << 7) | (wv << 6) | lane;
    Wt[(size_t)(2 * n) * 1024 + j] = (_Float16)s[k].x;
    Wt[(size_t)(2 * n + 1) * 1024 + j] = (_Float16)(-s[k].y);
  }
}

// ---------------- LDS-staged GEMM with fused NLL accumulation ----------------
#define GZ_NSTEP 13

__device__ __forceinline__ void stage_tiles(const _Float16* __restrict__ gA,
                                            const _Float16* __restrict__ gB,
                                            _Float16* sA, _Float16* sB,
                                            int k0, int wv, int lane) {
  const int rIn = lane >> 3;
  const int colh = ((lane & 7) ^ rIn) * 8;
  #pragma unroll
  for (int c = 0; c < 2; ++c) {
    const int chunk = wv * 2 + c;
    const size_t grow = (size_t)(chunk * 8 + rIn) * 1024 + k0 + colh;
    auto* la = (__attribute__((address_space(3))) void*)(sA + chunk * 512 + lane * 8);
    __builtin_amdgcn_global_load_lds(
        (const __attribute__((address_space(1))) void*)(gA + grow), la, 16, 0, 0);
    auto* lb = (__attribute__((address_space(3))) void*)(sB + chunk * 512 + lane * 8);
    __builtin_amdgcn_global_load_lds(
        (const __attribute__((address_space(1))) void*)(gB + grow), lb, 16, 0, 0);
  }
}

__device__ __forceinline__ int lds_off(int row, int slot) {
  return row * 64 + ((slot ^ (row & 7)) * 8);
}

__global__ __launch_bounds__(512) void gemm_z(const _Float16* __restrict__ Xh,
                                              const _Float16* __restrict__ Wt,
                                              float* __restrict__ qa, int B) {
  __shared__ _Float16 smA[2][128 * 64];
  __shared__ _Float16 smB[2][128 * 64];

  const int tid = threadIdx.x;
  const int lane = tid & 63;
  const int wv = tid >> 6;
  const int wm = wv >> 1;
  const int wn = wv & 1;
  const int row0 = blockIdx.x * 128;
  const int n0 = blockIdx.y * 128;

  const _Float16* gA = Xh + (size_t)row0 * 1024;
  const _Float16* gB = Wt + (size_t)n0 * 1024;

  const int lr = lane & 15;
  const int lq = lane >> 4;

  f32x4v acc[2][4];
  #pragma unroll
  for (int m = 0; m < 2; ++m)
    #pragma unroll
    for (int f = 0; f < 4; ++f) acc[m][f] = f32x4v{0.f, 0.f, 0.f, 0.f};

  stage_tiles(gA, gB, smA[0], smB[0], 0, wv, lane);
  __syncthreads();

  for (int t = 0; t < GZ_NSTEP; ++t) {
    const int cur = t & 1;
    if (t + 1 < GZ_NSTEP)
      stage_tiles(gA, gB, smA[cur ^ 1], smB[cur ^ 1], (t + 1) * 64, wv, lane);

    #pragma unroll
    for (int kk = 0; kk < 2; ++kk) {
      const int slot = kk * 4 + lq;
      f16x8 a[2], b[4];
      #pragma unroll
      for (int m = 0; m < 2; ++m) {
        const int row = wm * 32 + m * 16 + lr;
        a[m] = *reinterpret_cast<const f16x8*>(&smA[cur][lds_off(row, slot)]);
      }
      #pragma unroll
      for (int f = 0; f < 4; ++f) {
        const int row = wn * 64 + f * 16 + lr;
        b[f] = *reinterpret_cast<const f16x8*>(&smB[cur][lds_off(row, slot)]);
      }
      #pragma unroll
      for (int m = 0; m < 2; ++m)
        #pragma unroll
        for (int f = 0; f < 4; ++f)
          acc[m][f] = __builtin_amdgcn_mfma_f32_16x16x32_f16(a[m], b[f], acc[m][f], 0, 0, 0);
    }
    __syncthreads();
  }

  // Fused epilogue: p = |psi|^2 summed over the wave's 32 js (sign-uniform
  // chunk pp); atomicAdd sign-folded contributions into q0/q1/nn.
  const int pp = blockIdx.y * 2 + wn;
  const float s0 = (pp & 16) ? -1.f : 1.f;
  const float s1 = (pp & 8) ? -1.f : 1.f;
  #pragma unroll
  for (int m = 0; m < 2; ++m) {
    f32x4v p = f32x4v{0.f, 0.f, 0.f, 0.f};
    #pragma unroll
    for (int f = 0; f < 4; ++f) p += acc[m][f] * acc[m][f];
    #pragma unroll
    for (int msk = 1; msk < 16; msk <<= 1) {
      p.x += __shfl_xor(p.x, msk, 64);
      p.y += __shfl_xor(p.y, msk, 64);
      p.z += __shfl_xor(p.z, msk, 64);
      p.w += __shfl_xor(p.w, msk, 64);
    }
    if (lr == 0) {
      const int rbase = row0 + wm * 32 + m * 16 + lq * 4;
      const float pv[4] = {p.x, p.y, p.z, p.w};
      #pragma unroll
      for (int q = 0; q < 4; ++q) {
        const int row = rbase + q;
        atomicAdd(&qa[row], s0 * pv[q]);
        atomicAdd(&qa[B + row], s1 * pv[q]);
        atomicAdd(&qa[2 * B + row], pv[q]);
      }
    }
  }
}

// ---- NLL from q0/q1/nn rows; scalar atomicAdd into out[0] ----
__global__ __launch_bounds__(1024) void nll_rows(const float* __restrict__ qa,
                                                 const int* __restrict__ y,
                                                 float* __restrict__ out, int B,
                                                 float scale) {
  const int row = blockIdx.x * 1024 + threadIdx.x;
  const float q0 = qa[row], q1 = qa[B + row], nn = qa[2 * B + row];
  const float z0 = q0 / nn, z1 = q1 / nn;
  const float mx = fmaxf(z0, z1);
  const float lse = mx + logf(expf(z0 - mx) + expf(z1 - mx));
  const float ly = (y[row] == 0) ? z0 : z1;
  float s = lse - ly;
  #pragma unroll
  for (int msk = 1; msk < 64; msk <<= 1) s += __shfl_xor(s, msk, 64);
  __shared__ float red[16];
  if ((threadIdx.x & 63) == 0) red[threadIdx.x >> 6] = s;
  __syncthreads();
  if (threadIdx.x == 0) {
    float tot = 0.f;
    #pragma unroll
    for (int q = 0; q < 16; ++q) tot += red[q];
    atomicAdd(out, tot * scale);
  }
}

} // namespace

extern "C" void kernel_launch(void* const* d_in, const int* in_sizes, int n_in,
                              void* d_out, int out_size, void* d_ws, size_t ws_size,
                              hipStream_t stream) {
  const float* x  = (const float*)d_in[0];
  const int*   y  = (const int*)d_in[1];
  const float* w  = (const float*)d_in[2];
  const float* w1 = (const float*)d_in[3];
  const float* w2 = (const float*)d_in[4];
  float* out = (float*)d_out;

  const int B = in_sizes[0] / 784;      // 8192

  char* ws = (char*)d_ws;
  _Float16* Wt = (_Float16*)ws;                                  // 4 MB
  _Float16* Xh = (_Float16*)(ws + (size_t)2048 * 1024 * 2);      // 16 MB
  float*    qa = (float*)(ws + (size_t)2048 * 1024 * 2 + (size_t)B * 1024 * 2);
  float*    prog = qa + (size_t)3 * B;  // 69*64 floats

  make_prog<<<(3 * B + 1023) / 1024, 1024, 0, stream>>>(w, w1, w2, prog, qa, B, out);
  qprep<<<1024 + B, 128, 0, stream>>>(prog, x, Wt, Xh);
  gemm_z<<<dim3(B / 128, 16), 512, 0, stream>>>(Xh, Wt, qa, B);
  nll_rows<<<B / 1024, 1024, 0, stream>>>(qa, y, out, B, 1.0f / (float)B);
}

// Round 21
// 74.269 us; speedup vs baseline: 1.0760x; 1.0760x over previous
//
#include <hip/hip_runtime.h>

// CCQC classifier, GEMM formulation. R21 = R19 revert (R20's fused-NLL
// atomics caused cross-XCD contention in gemm_z's epilogue: 28 -> 41.5 us).
//   R19: 3 k-bits / 128-thread build blocks.
//   j = (k<<7)|(wv<<6)|lane, k in [0,8), 2 waves/block, 1 state/block.
//   Wires 0,1,2 (27 fused ops) -> in-register k-pairs (no barrier/shuffle).
//   Wire 3 (6 ops) -> single-wave-bit LDS exchange (6 barriers, 128 thr).
//   Wires 4-9 (36 ops) -> lane shuffles (DPP for j-bits 0,1).
//   Program: fused 69-op reversed-adjoint variant tables (matrix form for
//   bt>=7, coef form otherwise). nll atomicAdd (out zeroed by make_prog).
//   gemm_z: 128x128 BK=64 8-wave + XOR swizzle, fused |psi|^2 epilogue
//   -> 32 sign-uniform chunk partials (part[] store; NO row atomics).

namespace {

typedef float f32x2 __attribute__((ext_vector_type(2)));
typedef __fp16 fp16x2 __attribute__((ext_vector_type(2)));
typedef _Float16 f16x8 __attribute__((ext_vector_type(8)));
typedef float f32x4v __attribute__((ext_vector_type(4)));

// ---- packed dual-f32 ops (VOP3P), untied operands ----
__device__ __forceinline__ f32x2 pk_mul(f32x2 a, f32x2 b) {
  f32x2 d;
  asm("v_pk_mul_f32 %0, %1, %2" : "=v"(d) : "v"(a), "v"(b));
  return d;
}
__device__ __forceinline__ f32x2 pk_fma(f32x2 a, f32x2 b, f32x2 c) {
  f32x2 d;
  asm("v_pk_fma_f32 %0, %1, %2, %3" : "=v"(d) : "v"(a), "v"(b), "v"(c));
  return d;
}
__device__ __forceinline__ f32x2 pk_fma_swap1(f32x2 a, f32x2 b, f32x2 c) {
  f32x2 d;
  asm("v_pk_fma_f32 %0, %1, %2, %3 op_sel:[0,1,0] op_sel_hi:[1,0,1]"
      : "=v"(d) : "v"(a), "v"(b), "v"(c));
  return d;
}
__device__ __forceinline__ f32x2 cmulp(f32x2 cr2, f32x2 ci2, f32x2 v) {
  return pk_fma_swap1(ci2, v, pk_mul(cr2, v));
}
__device__ __forceinline__ f32x2 cmad(f32x2 acc, f32x2 cr2, f32x2 ci2, f32x2 v) {
  return pk_fma_swap1(ci2, v, pk_fma(cr2, v, acc));
}

__device__ __forceinline__ f32x2 shfl_xor2(f32x2 v, int lm) {
  f32x2 r;
  r.x = __shfl_xor(v.x, lm, 64);
  r.y = __shfl_xor(v.y, lm, 64);
  return r;
}
template <int CTRL>
__device__ __forceinline__ f32x2 dpp_xor2(f32x2 v) {
  f32x2 r;
  const int ix = __builtin_bit_cast(int, v.x);
  const int iy = __builtin_bit_cast(int, v.y);
  r.x = __builtin_bit_cast(float,
      __builtin_amdgcn_update_dpp(0, ix, CTRL, 0xF, 0xF, true));
  r.y = __builtin_bit_cast(float,
      __builtin_amdgcn_update_dpp(0, iy, CTRL, 0xF, 0xF, true));
  return r;
}
__device__ __forceinline__ f32x2 shfl_fast(f32x2 v, const int lm) {
  if (lm == 1) return dpp_xor2<0xB1>(v);
  if (lm == 2) return dpp_xor2<0x4E>(v);
  return shfl_xor2(v, lm);
}

struct c2 { float r, i; };
struct m2c { c2 a00, a01, a10, a11; };

__device__ __forceinline__ c2 cmul(c2 x, c2 y) { return {x.r*y.r - x.i*y.i, x.r*y.i + x.i*y.r}; }
__device__ __forceinline__ c2 cadd(c2 x, c2 y) { return {x.r + y.r, x.i + y.i}; }
__device__ __forceinline__ c2 conjc(c2 a) { return {a.r, -a.i}; }
__device__ __forceinline__ m2c mmul(m2c A, m2c B) {
  m2c C;
  C.a00 = cadd(cmul(A.a00, B.a00), cmul(A.a01, B.a10));
  C.a01 = cadd(cmul(A.a00, B.a01), cmul(A.a01, B.a11));
  C.a10 = cadd(cmul(A.a10, B.a00), cmul(A.a11, B.a10));
  C.a11 = cadd(cmul(A.a10, B.a01), cmul(A.a11, B.a11));
  return C;
}
__device__ __forceinline__ m2c madj(m2c U) {
  return { conjc(U.a00), conjc(U.a10), conjc(U.a01), conjc(U.a11) };
}
__device__ __forceinline__ m2c mrx(float t) {
  float c = cosf(0.5f * t), s = sinf(0.5f * t);
  return { {c, 0.f}, {0.f, -s}, {0.f, -s}, {c, 0.f} };
}
__device__ __forceinline__ m2c mrz(float t) {
  float c = cosf(0.5f * t), s = sinf(0.5f * t);
  return { {c, -s}, {0.f, 0.f}, {0.f, 0.f}, {c, s} };
}

// fusable(d,i): CU[i](d) absorbs U1[i](d+1). r(d)=1 (d even): i>=1; r=3: i>=3.
__device__ __forceinline__ bool fusable(int d, int i) {
  return (d & 1) ? (i >= 3) : (i >= 1);
}

// 69-op program, 64 floats/op.
//  bt>=7 (k-register target, wires 0..2): matrix form, M0@o[0], M1@o[16].
//  else: coef form, 4 variants v = hi + 2*c at o[v*8].
//  M0/M1: unfused no-ctrl: both adj; unfused ctrl: {I, adj(CU)};
//  fused: {adj(U1), adj(CU)*adj(U1)}.
// Thread 127 zeroes out[0] (nll atomicAdds into it each call).
__global__ void make_prog(const float* __restrict__ w, const float* __restrict__ w1,
                          const float* __restrict__ w2, float* __restrict__ prog,
                          float* __restrict__ outp) {
  const int t = threadIdx.x;
  if (t == 127) outp[0] = 0.f;
  int kind = -1, od = 0, oi = 0, p = 0;
  for (int dd = 0; dd < 5; ++dd) {
    const int d = 4 - dd;
    if (d == 4) { if (p == t) kind = 0; ++p; }
    for (int ii = 0; ii < 10; ++ii) {
      const int i = 9 - ii;
      if (p == t) { kind = (d <= 3 && fusable(d, i)) ? 2 : 1; od = d; oi = i; }
      ++p;
    }
    for (int ii = 0; ii < 10; ++ii) {
      const int i = 9 - ii;
      if (d >= 1 && fusable(d - 1, i)) continue;
      if (p == t) { kind = 3; od = d; oi = i; }
      ++p;
    }
  }
  if (kind < 0) return;

  auto u1mat = [&](int d, int i) -> m2c {
    const float* pw = w + (d * 10 + i) * 5;
    m2c U = mmul(mrx(pw[2]), mmul(mrz(pw[1]), mrx(pw[0])));
    if (i == 0 && d > 0) {
      m2c U0 = mmul(mrz(w2[d - 1]), mrx(w1[d - 1]));
      U = mmul(U, U0);
    }
    return U;
  };
  auto cumat = [&](int d, int i) -> m2c {
    const float* pw = w + (d * 10 + i) * 5;
    return mmul(mrx(pw[4]), mrz(pw[3]));
  };

  m2c M0{}, M1{};
  int bt = 9;
  if (kind == 0) {
    M0 = madj(mmul(mrz(w2[4]), mrx(w1[4]))); M1 = M0; bt = 9;
  } else if (kind == 1) {
    M1 = madj(cumat(od, oi));
    M0 = m2c{ {1.f, 0.f}, {0.f, 0.f}, {0.f, 0.f}, {1.f, 0.f} };
    bt = 9 - oi;
  } else if (kind == 2) {
    m2c V1 = madj(u1mat(od + 1, oi));
    m2c VC = madj(cumat(od, oi));
    M0 = V1; M1 = mmul(VC, V1);
    bt = 9 - oi;
  } else {
    M0 = madj(u1mat(od, oi)); M1 = M0; bt = 9 - oi;
  }

  float* o = prog + t * 64;
  if (bt >= 7) {
    const m2c* Ms[2] = {&M0, &M1};
    #pragma unroll
    for (int c = 0; c < 2; ++c) {
      const c2 e[4] = {Ms[c]->a00, Ms[c]->a01, Ms[c]->a10, Ms[c]->a11};
      #pragma unroll
      for (int q = 0; q < 4; ++q) {
        o[c*16 + q*4 + 0] = e[q].r; o[c*16 + q*4 + 1] = e[q].r;
        o[c*16 + q*4 + 2] = -e[q].i; o[c*16 + q*4 + 3] = e[q].i;
      }
    }
  } else {
    #pragma unroll
    for (int v = 0; v < 4; ++v) {
      const bool hi = (v & 1) != 0;
      const m2c& M = (v >> 1) ? M1 : M0;
      const c2 cA = hi ? M.a11 : M.a00;
      const c2 cB = hi ? M.a10 : M.a01;
      o[v*8+0] = cA.r; o[v*8+1] = cA.r; o[v*8+2] = -cA.i; o[v*8+3] = cA.i;
      o[v*8+4] = cB.r; o[v*8+5] = cB.r; o[v*8+6] = -cB.i; o[v*8+7] = cB.i;
    }
  }
}

struct CoefP { f32x2 Ar, Ai, Br, Bi; };
__device__ __forceinline__ CoefP ldcoef(const float* __restrict__ g, int v) {
  const float4* p = reinterpret_cast<const float4*>(g + v * 8);
  const float4 a = p[0], b = p[1];
  return { f32x2{a.x, a.y}, f32x2{a.z, a.w}, f32x2{b.x, b.y}, f32x2{b.z, b.w} };
}
struct MatP { f32x2 u00r, u00i, u01r, u01i, u10r, u10i, u11r, u11i; };
__device__ __forceinline__ MatP ldmat16(const float* __restrict__ g, int c) {
  const float4* p = reinterpret_cast<const float4*>(g + c * 16);
  const float4 a = p[0], b = p[1], cc = p[2], d = p[3];
  MatP m;
  m.u00r = f32x2{a.x, a.y};  m.u00i = f32x2{a.z, a.w};
  m.u01r = f32x2{b.x, b.y};  m.u01i = f32x2{b.z, b.w};
  m.u10r = f32x2{cc.x, cc.y}; m.u10i = f32x2{cc.z, cc.w};
  m.u11r = f32x2{d.x, d.y};  m.u11i = f32x2{d.z, d.w};
  return m;
}
__device__ __forceinline__ f32x2 capply(const CoefP& c, f32x2 own, f32x2 par) {
  return cmad(cmulp(c.Ar, c.Ai, own), c.Br, c.Bi, par);
}
__device__ __forceinline__ void mat_pair(const MatP& m, f32x2& a, f32x2& b) {
  const f32x2 na = cmad(cmulp(m.u00r, m.u00i, a), m.u01r, m.u01i, b);
  const f32x2 nb = cmad(cmulp(m.u10r, m.u10i, a), m.u11r, m.u11i, b);
  a = na; b = nb;
}

// One program op. j = (k<<7)|(wv<<6)|lane, k in [0,8), wv in {0,1}.
//   bt>=7: k-register pair (tm = 1<<(bt-7)), matrix form.
//   bt==6: cross-wave exchange (partner wv^1), coef form, 1 barrier.
//   bt<6: lane shuffle (lm = 1<<bt), coef form.
// ctrl bc: >=7 per-k (cb=bc-7); ==6 wave-uniform (c=wv); [0,6) per-lane; <0 none.
__device__ __forceinline__ void apply_op(f32x2 (&s)[8], f32x2* lxb, const int wv,
                                         const int lane, const float* __restrict__ g,
                                         const int bt, const int bc) {
  if (bt >= 7) {
    const int tm = 1 << (bt - 7);
    if (bc >= 7) {
      const int cb = bc - 7;
      const MatP m0 = ldmat16(g, 0), m1 = ldmat16(g, 1);
      #pragma unroll
      for (int k0 = 0; k0 < 8; ++k0) {
        if (k0 & tm) continue;
        const int k1 = k0 | tm;
        const MatP& m = ((k0 >> cb) & 1) ? m1 : m0;
        mat_pair(m, s[k0], s[k1]);
      }
    } else {
      int c = 0;
      if (bc == 6)      c = wv;
      else if (bc >= 0) c = (lane >> bc) & 1;
      const MatP m = ldmat16(g, c);
      #pragma unroll
      for (int k0 = 0; k0 < 8; ++k0) {
        if (k0 & tm) continue;
        const int k1 = k0 | tm;
        mat_pair(m, s[k0], s[k1]);
      }
    }
  } else if (bt == 6) {
    const int hi = wv;
    #pragma unroll
    for (int k = 0; k < 8; ++k) lxb[(wv * 8 + k) * 64 + lane] = s[k];
    __syncthreads();
    const int pw = wv ^ 1;
    f32x2 pp[8];
    #pragma unroll
    for (int k = 0; k < 8; ++k) pp[k] = lxb[(pw * 8 + k) * 64 + lane];
    if (bc >= 7) {
      const int cb = bc - 7;
      const CoefP c0 = ldcoef(g, hi), c1 = ldcoef(g, hi + 2);
      #pragma unroll
      for (int k = 0; k < 8; ++k) {
        const CoefP& cf = ((k >> cb) & 1) ? c1 : c0;
        s[k] = capply(cf, s[k], pp[k]);
      }
    } else {
      int c = 0;
      if (bc >= 0) c = (lane >> bc) & 1;   // bc==6 impossible (== bt)
      const CoefP cf = ldcoef(g, hi + 2 * c);
      #pragma unroll
      for (int k = 0; k < 8; ++k) s[k] = capply(cf, s[k], pp[k]);
    }
  } else {
    const int lm = 1 << bt;
    const int hi = (lane >> bt) & 1;
    if (bc >= 7) {
      const int cb = bc - 7;
      const CoefP c0 = ldcoef(g, hi), c1 = ldcoef(g, hi + 2);
      #pragma unroll
      for (int k = 0; k < 8; ++k) {
        const CoefP& cf = ((k >> cb) & 1) ? c1 : c0;
        const f32x2 p = shfl_fast(s[k], lm);
        s[k] = capply(cf, s[k], p);
      }
    } else {
      int c = 0;
      if (bc == 6)      c = wv;
      else if (bc >= 0) c = (lane >> bc) & 1;
      const CoefP cf = ldcoef(g, hi + 2 * c);
      #pragma unroll
      for (int k = 0; k < 8; ++k) {
        const f32x2 p = shfl_fast(s[k], lm);
        s[k] = capply(cf, s[k], p);
      }
    }
  }
}

// Fused prep, 128-thread blocks. Blocks <1024: build row n=blockIdx of U.
// Blocks >=1024: xconv one batch row (832 cols, packed cvt).
__global__ __launch_bounds__(128) void qprep(const float* __restrict__ prog,
                                             const float* __restrict__ x,
                                             _Float16* __restrict__ Wt,
                                             _Float16* __restrict__ Xh) {
  const int tid = threadIdx.x;
  if (blockIdx.x >= 1024) {
    const int b = blockIdx.x - 1024;   // batch row
    const int j = tid * 8;
    if (j >= 832) return;
    union { fp16x2 h2[4]; f16x8 h8; } u;
    if (j < 784) {
      const float4* p = reinterpret_cast<const float4*>(x + (size_t)b * 784 + j);
      const float4 v0 = p[0], v1 = p[1];
      u.h2[0] = __builtin_amdgcn_cvt_pkrtz(v0.x, v0.y);
      u.h2[1] = __builtin_amdgcn_cvt_pkrtz(v0.z, v0.w);
      u.h2[2] = __builtin_amdgcn_cvt_pkrtz(v1.x, v1.y);
      u.h2[3] = __builtin_amdgcn_cvt_pkrtz(v1.z, v1.w);
    } else {
      #pragma unroll
      for (int q = 0; q < 4; ++q) u.h2[q] = __builtin_amdgcn_cvt_pkrtz(0.f, 0.f);
    }
    *reinterpret_cast<f16x8*>(Xh + (size_t)b * 1024 + j) = u.h8;
    return;
  }

  // ---- build_W: 1 state, 8 regs/lane, 2 waves ----
  __shared__ f32x2 lx[2][1024];   // double-buffered exchange (2 x 8 KB)

  const int lane = tid & 63;
  const int wv = tid >> 6;        // 0..1 = j-bit 6
  const int n = blockIdx.x;

  f32x2 s[8];
  #pragma unroll
  for (int k = 0; k < 8; ++k) {
    const int j = (k << 7) | (wv << 6) | lane;
    s[k].x = (j == n) ? 1.f : 0.f;
    s[k].y = 0.f;
  }

  int p = 0, ph = 0;
  #pragma unroll
  for (int dd = 0; dd < 5; ++dd) {
    const int d = 4 - dd;
    if (d == 4) {
      apply_op(s, &lx[ph & 1][0], wv, lane, prog + p * 64, 9, -1);
      ++p;   // bt=9: k-reg op
    }
    const int r = (d & 1) ? 3 : 1;
    #pragma unroll
    for (int ii = 0; ii < 10; ++ii) {
      const int i = 9 - ii;
      const int c = (i + r) % 10;
      const int bt = 9 - i, bc = 9 - c;
      apply_op(s, &lx[ph & 1][0], wv, lane, prog + p * 64, bt, bc);
      ++p; if (bt == 6) ++ph;
    }
    #pragma unroll
    for (int ii = 0; ii < 10; ++ii) {
      const int i = 9 - ii;
      if (d >= 1 && fusable(d - 1, i)) continue;   // absorbed forward
      const int bt = 9 - i;
      apply_op(s, &lx[ph & 1][0], wv, lane, prog + p * 64, bt, -1);
      ++p; if (bt == 6) ++ph;
    }
  }

  // psi = U^dagger e_n => U[n][j] = (s.x, -s.y); j = (k<<7)|(wv<<6)|lane
  #pragma unroll
  for (int k = 0; k < 8; ++k) {
    const int j = (k << 7) | (wv << 6) | lane;
    Wt[(size_t)(2 * n) * 1024 + j] = (_Float16)s[k].x;
    Wt[(size_t)(2 * n + 1) * 1024 + j] = (_Float16)(-s[k].y);
  }
}

// ---------------- LDS-staged GEMM (unchanged from R11) ----------------
#define GZ_NSTEP 13

__device__ __forceinline__ void stage_tiles(const _Float16* __restrict__ gA,
                                            const _Float16* __restrict__ gB,
                                            _Float16* sA, _Float16* sB,
                                            int k0, int wv, int lane) {
  const int rIn = lane >> 3;
  const int colh = ((lane & 7) ^ rIn) * 8;
  #pragma unroll
  for (int c = 0; c < 2; ++c) {
    const int chunk = wv * 2 + c;
    const size_t grow = (size_t)(chunk * 8 + rIn) * 1024 + k0 + colh;
    auto* la = (__attribute__((address_space(3))) void*)(sA + chunk * 512 + lane * 8);
    __builtin_amdgcn_global_load_lds(
        (const __attribute__((address_space(1))) void*)(gA + grow), la, 16, 0, 0);
    auto* lb = (__attribute__((address_space(3))) void*)(sB + chunk * 512 + lane * 8);
    __builtin_amdgcn_global_load_lds(
        (const __attribute__((address_space(1))) void*)(gB + grow), lb, 16, 0, 0);
  }
}

__device__ __forceinline__ int lds_off(int row, int slot) {
  return row * 64 + ((slot ^ (row & 7)) * 8);
}

__global__ __launch_bounds__(512) void gemm_z(const _Float16* __restrict__ Xh,
                                              const _Float16* __restrict__ Wt,
                                              float* __restrict__ part, int B) {
  __shared__ _Float16 smA[2][128 * 64];
  __shared__ _Float16 smB[2][128 * 64];

  const int tid = threadIdx.x;
  const int lane = tid & 63;
  const int wv = tid >> 6;
  const int wm = wv >> 1;
  const int wn = wv & 1;
  const int row0 = blockIdx.x * 128;
  const int n0 = blockIdx.y * 128;

  const _Float16* gA = Xh + (size_t)row0 * 1024;
  const _Float16* gB = Wt + (size_t)n0 * 1024;

  const int lr = lane & 15;
  const int lq = lane >> 4;

  f32x4v acc[2][4];
  #pragma unroll
  for (int m = 0; m < 2; ++m)
    #pragma unroll
    for (int f = 0; f < 4; ++f) acc[m][f] = f32x4v{0.f, 0.f, 0.f, 0.f};

  stage_tiles(gA, gB, smA[0], smB[0], 0, wv, lane);
  __syncthreads();

  for (int t = 0; t < GZ_NSTEP; ++t) {
    const int cur = t & 1;
    if (t + 1 < GZ_NSTEP)
      stage_tiles(gA, gB, smA[cur ^ 1], smB[cur ^ 1], (t + 1) * 64, wv, lane);

    #pragma unroll
    for (int kk = 0; kk < 2; ++kk) {
      const int slot = kk * 4 + lq;
      f16x8 a[2], b[4];
      #pragma unroll
      for (int m = 0; m < 2; ++m) {
        const int row = wm * 32 + m * 16 + lr;
        a[m] = *reinterpret_cast<const f16x8*>(&smA[cur][lds_off(row, slot)]);
      }
      #pragma unroll
      for (int f = 0; f < 4; ++f) {
        const int row = wn * 64 + f * 16 + lr;
        b[f] = *reinterpret_cast<const f16x8*>(&smB[cur][lds_off(row, slot)]);
      }
      #pragma unroll
      for (int m = 0; m < 2; ++m)
        #pragma unroll
        for (int f = 0; f < 4; ++f)
          acc[m][f] = __builtin_amdgcn_mfma_f32_16x16x32_f16(a[m], b[f], acc[m][f], 0, 0, 0);
    }
    __syncthreads();
  }

  const int pp = blockIdx.y * 2 + wn;
  #pragma unroll
  for (int m = 0; m < 2; ++m) {
    f32x4v p = f32x4v{0.f, 0.f, 0.f, 0.f};
    #pragma unroll
    for (int f = 0; f < 4; ++f) p += acc[m][f] * acc[m][f];
    #pragma unroll
    for (int msk = 1; msk < 16; msk <<= 1) {
      p.x += __shfl_xor(p.x, msk, 64);
      p.y += __shfl_xor(p.y, msk, 64);
      p.z += __shfl_xor(p.z, msk, 64);
      p.w += __shfl_xor(p.w, msk, 64);
    }
    if (lr == 0) {
      const int rbase = row0 + wm * 32 + m * 16 + lq * 4;
      float* dst = part + (size_t)pp * B + rbase;
      dst[0] = p.x; dst[1] = p.y; dst[2] = p.z; dst[3] = p.w;
    }
  }
}

// ---- NLL: per-block partial, atomicAdd of scaled sum into out[0] ----
__global__ __launch_bounds__(256) void nll_part(const float* __restrict__ part,
                                                const int* __restrict__ y,
                                                float* __restrict__ out, int B,
                                                float scale) {
  const int row = blockIdx.x * 256 + threadIdx.x;
  float q0 = 0.f, q1 = 0.f, nn = 0.f;
  #pragma unroll
  for (int pp = 0; pp < 32; ++pp) {
    const float P = part[(size_t)pp * B + row];
    q0 += (pp & 16) ? -P : P;
    q1 += (pp & 8) ? -P : P;
    nn += P;
  }
  const float z0 = q0 / nn, z1 = q1 / nn;
  const float mx = fmaxf(z0, z1);
  const float lse = mx + logf(expf(z0 - mx) + expf(z1 - mx));
  const float ly = (y[row] == 0) ? z0 : z1;
  float s = lse - ly;
  #pragma unroll
  for (int msk = 1; msk < 64; msk <<= 1) s += __shfl_xor(s, msk, 64);
  __shared__ float red[4];
  if ((threadIdx.x & 63) == 0) red[threadIdx.x >> 6] = s;
  __syncthreads();
  if (threadIdx.x == 0)
    atomicAdd(out, (red[0] + red[1] + red[2] + red[3]) * scale);
}

} // namespace

extern "C" void kernel_launch(void* const* d_in, const int* in_sizes, int n_in,
                              void* d_out, int out_size, void* d_ws, size_t ws_size,
                              hipStream_t stream) {
  const float* x  = (const float*)d_in[0];
  const int*   y  = (const int*)d_in[1];
  const float* w  = (const float*)d_in[2];
  const float* w1 = (const float*)d_in[3];
  const float* w2 = (const float*)d_in[4];
  float* out = (float*)d_out;

  const int B = in_sizes[0] / 784;      // 8192

  char* ws = (char*)d_ws;
  _Float16* Wt   = (_Float16*)ws;                                // 4 MB
  _Float16* Xh   = (_Float16*)(ws + (size_t)2048 * 1024 * 2);    // 16 MB
  float*    part = (float*)(ws + (size_t)2048 * 1024 * 2 + (size_t)B * 1024 * 2);
  float*    prog = part + (size_t)32 * B;   // 69*64 floats

  make_prog<<<1, 128, 0, stream>>>(w, w1, w2, prog, out);
  qprep<<<1024 + B, 128, 0, stream>>>(prog, x, Wt, Xh);
  gemm_z<<<dim3(B / 128, 16), 512, 0, stream>>>(Xh, Wt, part, B);
  nll_part<<<B / 256, 256, 0, stream>>>(part, y, out, B, 1.0f / (float)B);
}